// Round 1
// baseline (889.329 us; speedup 1.0000x reference)
//
#include <hip/hip_runtime.h>

#define BB 8192
#define TT 10
#define FF 561
#define FP 576   // 561 padded to 18*32
#define HH 256
#define OO 12

typedef __attribute__((ext_vector_type(8))) __bf16 bf16x8;
typedef __attribute__((ext_vector_type(4))) float f32x4;

__device__ __forceinline__ unsigned short f2bf(float f) {
  unsigned int u = __float_as_uint(f);
  u += 0x7fffu + ((u >> 16) & 1u);   // round-to-nearest-even
  return (unsigned short)(u >> 16);
}
__device__ __forceinline__ float bf2f(unsigned short s) {
  return __uint_as_float(((unsigned int)s) << 16);
}
__device__ __forceinline__ float sigm(float x) { return 1.f / (1.f + __expf(-x)); }
__device__ __forceinline__ float tanh_fast(float x) { return 1.f - 2.f / (__expf(2.f * x) + 1.f); }

__device__ __forceinline__ void gl_lds16(const unsigned short* g, unsigned short* l) {
  __builtin_amdgcn_global_load_lds(
      (const __attribute__((address_space(1))) unsigned int*)g,
      (__attribute__((address_space(3))) unsigned int*)l, 16, 0, 0);
}

// Convert inputs [81920,561] f32 -> bf16 zero-padded [81920,576]
__global__ void conv_inputs(const float* __restrict__ in, unsigned short* __restrict__ Ain) {
  int idx = blockIdx.x * 256 + threadIdx.x;  // over 81920*144, 4 elems each
  if (idx >= 81920 * 144) return;
  int c4 = (idx % 144) * 4;
  size_t row = idx / 144;
  const float* src = in + row * 561 + c4;
  ushort4 v;
  v.x = f2bf(c4 + 0 < 561 ? src[0] : 0.f);
  v.y = f2bf(c4 + 1 < 561 ? src[1] : 0.f);
  v.z = f2bf(c4 + 2 < 561 ? src[2] : 0.f);
  v.w = f2bf(c4 + 3 < 561 ? src[3] : 0.f);
  *(ushort4*)(Ain + row * 576 + c4) = v;
}

// Build bf16 weights:
//  Wib [256][576]: W_inp zero-padded
//  W0p/W1p [1024][512]: permuted fused [Wih|Whh];
//    out row n' -> (h=(n'>>7)*32+(n'&31), gate=(n'>>5)&3), src row = gate*256+h
__global__ void conv_weights(const float* __restrict__ Winp,
                             const float* __restrict__ Wih0, const float* __restrict__ Whh0,
                             const float* __restrict__ Wih1, const float* __restrict__ Whh1,
                             unsigned short* __restrict__ Wib,
                             unsigned short* __restrict__ W0p,
                             unsigned short* __restrict__ W1p) {
  int idx = blockIdx.x * 256 + threadIdx.x;
  if (idx < 256 * 576) {
    int kk = idx % 576, n = idx / 576;
    Wib[idx] = f2bf(kk < 561 ? Winp[n * 561 + kk] : 0.f);
    return;
  }
  idx -= 256 * 576;
  if (idx < 1024 * 512) {
    int kk = idx % 512, np = idx / 512;
    int h = (np >> 7) * 32 + (np & 31), g = (np >> 5) & 3;
    int sr = g * 256 + h;
    float v = kk < 256 ? Wih0[sr * 256 + kk] : Whh0[sr * 256 + kk - 256];
    W0p[idx] = f2bf(v);
    return;
  }
  idx -= 1024 * 512;
  if (idx < 1024 * 512) {
    int kk = idx % 512, np = idx / 512;
    int h = (np >> 7) * 32 + (np & 31), g = (np >> 5) & 3;
    int sr = g * 256 + h;
    float v = kk < 256 ? Wih1[sr * 256 + kk] : Whh1[sr * 256 + kk - 256];
    W1p[idx] = f2bf(v);
  }
}

// MODE 0: C[row][col] = A@W^T + biasA, store bf16 at hout (ldc=HH). Grid (M/128, N/128).
// MODE 1: fused LSTM cell. N=1024 (gate-permuted), block nb owns h in [nb*32, nb*32+32).
// Dual A source: k < K0 from A0 (lda0), else A1 (lda1). BK=32, 128x128 tile, 4 waves,
// each wave = 32 rows x 128 cols (2x8 grid of 16x16 MFMA).
template <int MODE>
__global__ __launch_bounds__(256, 2) void gemm_k(
    const unsigned short* __restrict__ A0, int lda0, int K0,
    const unsigned short* __restrict__ A1, int lda1,
    const unsigned short* __restrict__ W, int K,
    const float* __restrict__ biasA, const float* __restrict__ biasB,
    float* __restrict__ cbuf,
    unsigned short* __restrict__ hout,
    float* __restrict__ hf32, float* __restrict__ cf32) {
  __shared__ __align__(16) unsigned short As[128 * 32];
  __shared__ __align__(16) unsigned short Bs[128 * 32];
  const int tid = threadIdx.x;
  const int w = tid >> 6, lane = tid & 63, quad = lane >> 4, l15 = lane & 15;
  const int mb = blockIdx.x, nb = blockIdx.y;

  f32x4 acc[2][8];
#pragma unroll
  for (int i = 0; i < 2; ++i)
#pragma unroll
    for (int j = 0; j < 8; ++j) acc[i][j] = (f32x4){0.f, 0.f, 0.f, 0.f};

  const int r0 = tid >> 2;          // staging row (chunk / 4)
  const int cc = (tid & 3) * 8;     // staging col (8 bf16 = 16B chunks)

  for (int k0 = 0; k0 < K; k0 += 32) {
    __syncthreads();
    const unsigned short* Asrc;
    int ldA, kk;
    if (k0 < K0) { Asrc = A0; ldA = lda0; kk = k0; }
    else         { Asrc = A1; ldA = lda1; kk = k0 - K0; }
    gl_lds16(Asrc + (size_t)(mb * 128 + r0) * ldA + kk + cc, &As[tid * 8]);
    gl_lds16(Asrc + (size_t)(mb * 128 + 64 + r0) * ldA + kk + cc, &As[2048 + tid * 8]);
    gl_lds16(W + (size_t)(nb * 128 + r0) * K + k0 + cc, &Bs[tid * 8]);
    gl_lds16(W + (size_t)(nb * 128 + 64 + r0) * K + k0 + cc, &Bs[2048 + tid * 8]);
    __syncthreads();  // compiler emits vmcnt(0) drain before barrier

    bf16x8 af[2], bfr[8];
#pragma unroll
    for (int mt = 0; mt < 2; ++mt)
      af[mt] = *(const bf16x8*)&As[(w * 32 + mt * 16 + l15) * 32 + quad * 8];
#pragma unroll
    for (int nt = 0; nt < 8; ++nt)
      bfr[nt] = *(const bf16x8*)&Bs[(nt * 16 + l15) * 32 + quad * 8];
#pragma unroll
    for (int mt = 0; mt < 2; ++mt)
#pragma unroll
      for (int nt = 0; nt < 8; ++nt)
        acc[mt][nt] = __builtin_amdgcn_mfma_f32_16x16x32_bf16(af[mt], bfr[nt], acc[mt][nt], 0, 0, 0);
  }

  if constexpr (MODE == 0) {
#pragma unroll
    for (int mt = 0; mt < 2; ++mt) {
      int rowb = mb * 128 + w * 32 + mt * 16 + quad * 4;
#pragma unroll
      for (int nt = 0; nt < 8; ++nt) {
        int col = nb * 128 + nt * 16 + l15;
        float bv = biasA[col];
#pragma unroll
        for (int r = 0; r < 4; ++r)
          hout[(size_t)(rowb + r) * HH + col] = f2bf(acc[mt][nt][r] + bv);
      }
    }
  } else {
#pragma unroll
    for (int hb = 0; hb < 2; ++hb) {
      int hg = nb * 32 + hb * 16 + l15;
      float bI = biasA[hg] + biasB[hg];
      float bF = biasA[256 + hg] + biasB[256 + hg];
      float bG = biasA[512 + hg] + biasB[512 + hg];
      float bO = biasA[768 + hg] + biasB[768 + hg];
#pragma unroll
      for (int mt = 0; mt < 2; ++mt) {
        int rowb = mb * 128 + w * 32 + mt * 16 + quad * 4;
#pragma unroll
        for (int r = 0; r < 4; ++r) {
          size_t idx = (size_t)(rowb + r) * HH + hg;
          float xi = acc[mt][0 + hb][r] + bI;
          float xf = acc[mt][2 + hb][r] + bF;
          float xg = acc[mt][4 + hb][r] + bG;
          float xo = acc[mt][6 + hb][r] + bO;
          float c_old = cbuf[idx];
          float cn = sigm(xf) * c_old + sigm(xi) * tanh_fast(xg);
          float hn = sigm(xo) * tanh_fast(cn);
          cbuf[idx] = cn;
          hout[idx] = f2bf(hn);
          if (hf32) hf32[idx] = hn;
          if (cf32) cf32[idx] = cn;
        }
      }
    }
  }
}

// outputs[b,t,o] = sum_h hs[t+1][b][h] * W_out[o][h] + b_out[o]
__global__ void out_gemm(const unsigned short* __restrict__ hs,
                         const float* __restrict__ Wout, const float* __restrict__ bout,
                         float* __restrict__ out) {
  int idx = blockIdx.x * 256 + threadIdx.x;
  if (idx >= BB * TT * OO) return;
  int o = idx % OO;
  int bt = idx / OO;
  int t = bt % TT;
  int b = bt / TT;
  const unsigned short* hrow = hs + ((size_t)(t + 1) * BB + b) * HH;
  const float* wrow = Wout + o * HH;
  float s = 0.f;
#pragma unroll 4
  for (int k = 0; k < HH; k += 2) {
    unsigned int u = *(const unsigned int*)(hrow + k);
    s += bf2f((unsigned short)(u & 0xffffu)) * wrow[k] +
         bf2f((unsigned short)(u >> 16)) * wrow[k + 1];
  }
  out[idx] = s + bout[o];
}

extern "C" void kernel_launch(void* const* d_in, const int* in_sizes, int n_in,
                              void* d_out, int out_size, void* d_ws, size_t ws_size,
                              hipStream_t stream) {
  const float* inputs = (const float*)d_in[0];
  const float* W_inp  = (const float*)d_in[1];
  const float* b_inp  = (const float*)d_in[2];
  const float* Wih0   = (const float*)d_in[3];
  const float* Whh0   = (const float*)d_in[4];
  const float* bih0   = (const float*)d_in[5];
  const float* bhh0   = (const float*)d_in[6];
  const float* Wih1   = (const float*)d_in[7];
  const float* Whh1   = (const float*)d_in[8];
  const float* bih1   = (const float*)d_in[9];
  const float* bhh1   = (const float*)d_in[10];
  const float* W_out  = (const float*)d_in[11];
  const float* b_out  = (const float*)d_in[12];
  float* out = (float*)d_out;

  char* ws = (char*)d_ws;
  size_t off = 0;
  auto alloc = [&](size_t bytes) {
    char* p = ws + off;
    off += (bytes + 255) & ~(size_t)255;
    return p;
  };
  unsigned short* Ain = (unsigned short*)alloc((size_t)81920 * FP * 2);
  unsigned short* xp  = (unsigned short*)alloc((size_t)81920 * HH * 2);
  unsigned short* Wib = (unsigned short*)alloc((size_t)256 * FP * 2);
  unsigned short* W0p = (unsigned short*)alloc((size_t)1024 * 512 * 2);
  unsigned short* W1p = (unsigned short*)alloc((size_t)1024 * 512 * 2);
  unsigned short* h0s = (unsigned short*)alloc((size_t)2 * BB * HH * 2);   // ping-pong
  unsigned short* hs  = (unsigned short*)alloc((size_t)(TT + 1) * BB * HH * 2); // slot0=zeros
  float* c0 = (float*)alloc((size_t)BB * HH * 4);
  float* c1 = (float*)alloc((size_t)BB * HH * 4);

  // zero-init states (ws is re-poisoned 0xAA before every timed launch)
  hipMemsetAsync(h0s, 0, (size_t)BB * HH * 2, stream);   // slot 0 only
  hipMemsetAsync(hs, 0, (size_t)BB * HH * 2, stream);    // slot 0 only
  hipMemsetAsync(c0, 0, (size_t)BB * HH * 4, stream);
  hipMemsetAsync(c1, 0, (size_t)BB * HH * 4, stream);

  conv_inputs<<<(81920 * 144 + 255) / 256, 256, 0, stream>>>(inputs, Ain);
  {
    int nthr = 256 * 576 + 2 * 1024 * 512;
    conv_weights<<<(nthr + 255) / 256, 256, 0, stream>>>(W_inp, Wih0, Whh0, Wih1, Whh1,
                                                         Wib, W0p, W1p);
  }

  // xp[81920,256] = Ain @ Wib^T + b_inp   (M=81920 N=256 K=576)
  gemm_k<0><<<dim3(640, 2), 256, 0, stream>>>(
      Ain, FP, FP, (const unsigned short*)nullptr, 0,
      Wib, FP, b_inp, (const float*)nullptr,
      (float*)nullptr, xp, (float*)nullptr, (float*)nullptr);

  float* hn_out = out + (size_t)BB * TT * OO;       // h_n [2][B][H]
  float* cn_out = hn_out + (size_t)2 * BB * HH;     // c_n [2][B][H]

  for (int t = 0; t < TT; ++t) {
    const unsigned short* h0_prev = h0s + (size_t)(t & 1) * BB * HH;
    unsigned short* h0_new       = h0s + (size_t)((t + 1) & 1) * BB * HH;
    const unsigned short* xpt = xp + (size_t)t * HH;           // row stride TT*HH
    const unsigned short* h1_prev = hs + (size_t)t * BB * HH;
    unsigned short* h1_new        = hs + (size_t)(t + 1) * BB * HH;
    bool last = (t == TT - 1);

    // layer 0: gates = [xp_t | h0_prev] @ W0p^T  -> cell -> h0_new, c0
    gemm_k<1><<<dim3(64, 8), 256, 0, stream>>>(
        xpt, TT * HH, 256, h0_prev, HH,
        W0p, 512, bih0, bhh0, c0, h0_new,
        last ? hn_out : (float*)nullptr,
        last ? cn_out : (float*)nullptr);

    // layer 1: gates = [h0_new | h1_prev] @ W1p^T -> cell -> h1_new (=hs slot t+1), c1
    gemm_k<1><<<dim3(64, 8), 256, 0, stream>>>(
        h0_new, HH, 256, h1_prev, HH,
        W1p, 512, bih1, bhh1, c1, h1_new,
        last ? hn_out + (size_t)BB * HH : (float*)nullptr,
        last ? cn_out + (size_t)BB * HH : (float*)nullptr);
  }

  out_gemm<<<(BB * TT * OO + 255) / 256, 256, 0, stream>>>(hs, W_out, b_out, out);
}

// Round 2
// 776.907 us; speedup vs baseline: 1.1447x; 1.1447x over previous
//
#include <hip/hip_runtime.h>

#define BB 8192
#define TT 10
#define FF 561
#define FP 576   // 561 padded to 18*32
#define HH 256
#define OO 12

typedef __attribute__((ext_vector_type(8))) __bf16 bf16x8;
typedef __attribute__((ext_vector_type(4))) float f32x4;

__device__ __forceinline__ unsigned short f2bf(float f) {
  unsigned int u = __float_as_uint(f);
  u += 0x7fffu + ((u >> 16) & 1u);   // round-to-nearest-even
  return (unsigned short)(u >> 16);
}
__device__ __forceinline__ float bf2f(unsigned short s) {
  return __uint_as_float(((unsigned int)s) << 16);
}
__device__ __forceinline__ float sigm(float x) { return 1.f / (1.f + __expf(-x)); }
__device__ __forceinline__ float tanh_fast(float x) { return 1.f - 2.f / (__expf(2.f * x) + 1.f); }

__device__ __forceinline__ void gl_lds16(const unsigned short* g, unsigned short* l) {
  __builtin_amdgcn_global_load_lds(
      (const __attribute__((address_space(1))) unsigned int*)g,
      (__attribute__((address_space(3))) unsigned int*)l, 16, 0, 0);
}

// Convert inputs [81920,561] f32 -> bf16 zero-padded [81920,576]
__global__ void conv_inputs(const float* __restrict__ in, unsigned short* __restrict__ Ain) {
  int idx = blockIdx.x * 256 + threadIdx.x;  // over 81920*144, 4 elems each
  if (idx >= 81920 * 144) return;
  int c4 = (idx % 144) * 4;
  size_t row = idx / 144;
  const float* src = in + row * 561 + c4;
  ushort4 v;
  v.x = f2bf(c4 + 0 < 561 ? src[0] : 0.f);
  v.y = f2bf(c4 + 1 < 561 ? src[1] : 0.f);
  v.z = f2bf(c4 + 2 < 561 ? src[2] : 0.f);
  v.w = f2bf(c4 + 3 < 561 ? src[3] : 0.f);
  *(ushort4*)(Ain + row * 576 + c4) = v;
}

// Build bf16 weights:
//  Wib [256][576]: W_inp zero-padded
//  W0p/W1p [1024][512]: permuted fused [Wih|Whh];
//    out row n' -> (h=(n'>>7)*32+(n'&31), gate=(n'>>5)&3), src row = gate*256+h
//  Wob [16][256]: W_out zero-padded rows 12..15
__global__ void conv_weights(const float* __restrict__ Winp,
                             const float* __restrict__ Wih0, const float* __restrict__ Whh0,
                             const float* __restrict__ Wih1, const float* __restrict__ Whh1,
                             const float* __restrict__ Wout,
                             unsigned short* __restrict__ Wib,
                             unsigned short* __restrict__ W0p,
                             unsigned short* __restrict__ W1p,
                             unsigned short* __restrict__ Wob) {
  int idx = blockIdx.x * 256 + threadIdx.x;
  if (idx < 256 * 576) {
    int kk = idx % 576, n = idx / 576;
    Wib[idx] = f2bf(kk < 561 ? Winp[n * 561 + kk] : 0.f);
    return;
  }
  idx -= 256 * 576;
  if (idx < 1024 * 512) {
    int kk = idx % 512, np = idx / 512;
    int h = (np >> 7) * 32 + (np & 31), g = (np >> 5) & 3;
    int sr = g * 256 + h;
    float v = kk < 256 ? Wih0[sr * 256 + kk] : Whh0[sr * 256 + kk - 256];
    W0p[idx] = f2bf(v);
    return;
  }
  idx -= 1024 * 512;
  if (idx < 1024 * 512) {
    int kk = idx % 512, np = idx / 512;
    int h = (np >> 7) * 32 + (np & 31), g = (np >> 5) & 3;
    int sr = g * 256 + h;
    float v = kk < 256 ? Wih1[sr * 256 + kk] : Whh1[sr * 256 + kk - 256];
    W1p[idx] = f2bf(v);
    return;
  }
  idx -= 1024 * 512;
  if (idx < 16 * 256) {
    int kk = idx % 256, o = idx / 256;
    Wob[idx] = f2bf(o < OO ? Wout[o * 256 + kk] : 0.f);
  }
}

// MODE 0: C[row][col] = A@W^T + biasA, store bf16 at hout (ldc=HH). Grid (M/128, N/128).
// MODE 1: fused LSTM cell. N=1024 (gate-permuted), block nb owns h in [nb*32, nb*32+32).
// Dual A source: k < K0 from A0 (lda0), else A1 (lda1). BK=32, 128x128 tile, 4 waves,
// each wave = 32 rows x 128 cols (2x8 grid of 16x16 MFMA).
template <int MODE>
__global__ __launch_bounds__(256, 2) void gemm_k(
    const unsigned short* __restrict__ A0, int lda0, int K0,
    const unsigned short* __restrict__ A1, int lda1,
    const unsigned short* __restrict__ W, int K,
    const float* __restrict__ biasA, const float* __restrict__ biasB,
    float* __restrict__ cbuf,
    unsigned short* __restrict__ hout,
    float* __restrict__ hf32, float* __restrict__ cf32) {
  __shared__ __align__(16) unsigned short As[128 * 32];
  __shared__ __align__(16) unsigned short Bs[128 * 32];
  const int tid = threadIdx.x;
  const int w = tid >> 6, lane = tid & 63, quad = lane >> 4, l15 = lane & 15;
  const int mb = blockIdx.x, nb = blockIdx.y;

  f32x4 acc[2][8];
#pragma unroll
  for (int i = 0; i < 2; ++i)
#pragma unroll
    for (int j = 0; j < 8; ++j) acc[i][j] = (f32x4){0.f, 0.f, 0.f, 0.f};

  const int r0 = tid >> 2;          // staging row (chunk / 4)
  const int cc = (tid & 3) * 8;     // staging col (8 bf16 = 16B chunks)

  for (int k0 = 0; k0 < K; k0 += 32) {
    __syncthreads();
    const unsigned short* Asrc;
    int ldA, kk;
    if (k0 < K0) { Asrc = A0; ldA = lda0; kk = k0; }
    else         { Asrc = A1; ldA = lda1; kk = k0 - K0; }
    gl_lds16(Asrc + (size_t)(mb * 128 + r0) * ldA + kk + cc, &As[tid * 8]);
    gl_lds16(Asrc + (size_t)(mb * 128 + 64 + r0) * ldA + kk + cc, &As[2048 + tid * 8]);
    gl_lds16(W + (size_t)(nb * 128 + r0) * K + k0 + cc, &Bs[tid * 8]);
    gl_lds16(W + (size_t)(nb * 128 + 64 + r0) * K + k0 + cc, &Bs[2048 + tid * 8]);
    __syncthreads();  // compiler emits vmcnt(0) drain before barrier

    bf16x8 af[2], bfr[8];
#pragma unroll
    for (int mt = 0; mt < 2; ++mt)
      af[mt] = *(const bf16x8*)&As[(w * 32 + mt * 16 + l15) * 32 + quad * 8];
#pragma unroll
    for (int nt = 0; nt < 8; ++nt)
      bfr[nt] = *(const bf16x8*)&Bs[(nt * 16 + l15) * 32 + quad * 8];
#pragma unroll
    for (int mt = 0; mt < 2; ++mt)
#pragma unroll
      for (int nt = 0; nt < 8; ++nt)
        acc[mt][nt] = __builtin_amdgcn_mfma_f32_16x16x32_bf16(af[mt], bfr[nt], acc[mt][nt], 0, 0, 0);
  }

  if constexpr (MODE == 0) {
#pragma unroll
    for (int mt = 0; mt < 2; ++mt) {
      int rowb = mb * 128 + w * 32 + mt * 16 + quad * 4;
#pragma unroll
      for (int nt = 0; nt < 8; ++nt) {
        int col = nb * 128 + nt * 16 + l15;
        float bv = biasA[col];
#pragma unroll
        for (int r = 0; r < 4; ++r)
          hout[(size_t)(rowb + r) * HH + col] = f2bf(acc[mt][nt][r] + bv);
      }
    }
  } else {
#pragma unroll
    for (int hb = 0; hb < 2; ++hb) {
      int hg = nb * 32 + hb * 16 + l15;
      float bI = biasA[hg] + biasB[hg];
      float bF = biasA[256 + hg] + biasB[256 + hg];
      float bG = biasA[512 + hg] + biasB[512 + hg];
      float bO = biasA[768 + hg] + biasB[768 + hg];
#pragma unroll
      for (int mt = 0; mt < 2; ++mt) {
        int rowb = mb * 128 + w * 32 + mt * 16 + quad * 4;
#pragma unroll
        for (int r = 0; r < 4; ++r) {
          size_t idx = (size_t)(rowb + r) * HH + hg;
          float xi = acc[mt][0 + hb][r] + bI;
          float xf = acc[mt][2 + hb][r] + bF;
          float xg = acc[mt][4 + hb][r] + bG;
          float xo = acc[mt][6 + hb][r] + bO;
          float c_old = cbuf[idx];
          float cn = sigm(xf) * c_old + sigm(xi) * tanh_fast(xg);
          float hn = sigm(xo) * tanh_fast(cn);
          cbuf[idx] = cn;
          hout[idx] = f2bf(hn);
          if (hf32) hf32[idx] = hn;
          if (cf32) cf32[idx] = cn;
        }
      }
    }
  }
}

// Output projection as MFMA GEMM: out[m=t*B+b][o] = hs[m+B][:] . Wob[o][:] + bout[o]
// M=81920, N=16 (12 used), K=256. One 16x16 tile per wave, 64 rows per block.
__global__ __launch_bounds__(256) void out_gemm_mfma(
    const unsigned short* __restrict__ hs,   // [(T+1)*B][HH], slots 1..T hold h1(t)
    const unsigned short* __restrict__ Wob,  // [16][HH] bf16, rows 12..15 zero
    const float* __restrict__ bout,
    float* __restrict__ out) {               // [B][T][OO]
  const int tid = threadIdx.x;
  const int w = tid >> 6, lane = tid & 63, quad = lane >> 4, l15 = lane & 15;
  const int m0 = blockIdx.x * 64 + w * 16;   // m = t*B + b
  const unsigned short* arow = hs + (size_t)(m0 + l15 + BB) * HH + quad * 8;
  const unsigned short* brow = Wob + l15 * HH + quad * 8;
  f32x4 acc = (f32x4){0.f, 0.f, 0.f, 0.f};
#pragma unroll
  for (int k0 = 0; k0 < 8; ++k0) {
    bf16x8 a = *(const bf16x8*)(arow + k0 * 32);
    bf16x8 b = *(const bf16x8*)(brow + k0 * 32);
    acc = __builtin_amdgcn_mfma_f32_16x16x32_bf16(a, b, acc, 0, 0, 0);
  }
  const int o = l15;
  if (o < OO) {
    float bv = bout[o];
#pragma unroll
    for (int r = 0; r < 4; ++r) {
      int m = m0 + quad * 4 + r;
      int b = m & (BB - 1);
      int t = m >> 13;                       // m / BB
      out[((size_t)b * TT + t) * OO + o] = acc[r] + bv;
    }
  }
}

extern "C" void kernel_launch(void* const* d_in, const int* in_sizes, int n_in,
                              void* d_out, int out_size, void* d_ws, size_t ws_size,
                              hipStream_t stream) {
  const float* inputs = (const float*)d_in[0];
  const float* W_inp  = (const float*)d_in[1];
  const float* b_inp  = (const float*)d_in[2];
  const float* Wih0   = (const float*)d_in[3];
  const float* Whh0   = (const float*)d_in[4];
  const float* bih0   = (const float*)d_in[5];
  const float* bhh0   = (const float*)d_in[6];
  const float* Wih1   = (const float*)d_in[7];
  const float* Whh1   = (const float*)d_in[8];
  const float* bih1   = (const float*)d_in[9];
  const float* bhh1   = (const float*)d_in[10];
  const float* W_out  = (const float*)d_in[11];
  const float* b_out  = (const float*)d_in[12];
  float* out = (float*)d_out;

  char* ws = (char*)d_ws;
  size_t off = 0;
  auto alloc = [&](size_t bytes) {
    char* p = ws + off;
    off += (bytes + 255) & ~(size_t)255;
    return p;
  };
  unsigned short* Ain = (unsigned short*)alloc((size_t)81920 * FP * 2);
  unsigned short* xp  = (unsigned short*)alloc((size_t)81920 * HH * 2);
  unsigned short* Wib = (unsigned short*)alloc((size_t)256 * FP * 2);
  unsigned short* W0p = (unsigned short*)alloc((size_t)1024 * 512 * 2);
  unsigned short* W1p = (unsigned short*)alloc((size_t)1024 * 512 * 2);
  unsigned short* Wob = (unsigned short*)alloc((size_t)16 * HH * 2);
  unsigned short* h0s = (unsigned short*)alloc((size_t)2 * BB * HH * 2);   // ping-pong
  unsigned short* hs  = (unsigned short*)alloc((size_t)(TT + 1) * BB * HH * 2); // slot0=zeros
  float* c0 = (float*)alloc((size_t)BB * HH * 4);
  float* c1 = (float*)alloc((size_t)BB * HH * 4);

  // zero-init states (ws is re-poisoned 0xAA before every timed launch)
  hipMemsetAsync(h0s, 0, (size_t)BB * HH * 2, stream);   // slot 0 only
  hipMemsetAsync(hs, 0, (size_t)BB * HH * 2, stream);    // slot 0 only
  hipMemsetAsync(c0, 0, (size_t)BB * HH * 4, stream);
  hipMemsetAsync(c1, 0, (size_t)BB * HH * 4, stream);

  conv_inputs<<<(81920 * 144 + 255) / 256, 256, 0, stream>>>(inputs, Ain);
  {
    int nthr = 256 * 576 + 2 * 1024 * 512 + 16 * 256;
    conv_weights<<<(nthr + 255) / 256, 256, 0, stream>>>(W_inp, Wih0, Whh0, Wih1, Whh1,
                                                         W_out, Wib, W0p, W1p, Wob);
  }

  // xp[81920,256] = Ain @ Wib^T + b_inp   (M=81920 N=256 K=576)
  gemm_k<0><<<dim3(640, 2), 256, 0, stream>>>(
      Ain, FP, FP, (const unsigned short*)nullptr, 0,
      Wib, FP, b_inp, (const float*)nullptr,
      (float*)nullptr, xp, (float*)nullptr, (float*)nullptr);

  float* hn_out = out + (size_t)BB * TT * OO;       // h_n [2][B][H]
  float* cn_out = hn_out + (size_t)2 * BB * HH;     // c_n [2][B][H]

  for (int t = 0; t < TT; ++t) {
    const unsigned short* h0_prev = h0s + (size_t)(t & 1) * BB * HH;
    unsigned short* h0_new       = h0s + (size_t)((t + 1) & 1) * BB * HH;
    const unsigned short* xpt = xp + (size_t)t * HH;           // row stride TT*HH
    const unsigned short* h1_prev = hs + (size_t)t * BB * HH;
    unsigned short* h1_new        = hs + (size_t)(t + 1) * BB * HH;
    bool last = (t == TT - 1);

    // layer 0: gates = [xp_t | h0_prev] @ W0p^T  -> cell -> h0_new, c0
    gemm_k<1><<<dim3(64, 8), 256, 0, stream>>>(
        xpt, TT * HH, 256, h0_prev, HH,
        W0p, 512, bih0, bhh0, c0, h0_new,
        last ? hn_out : (float*)nullptr,
        last ? cn_out : (float*)nullptr);

    // layer 1: gates = [h0_new | h1_prev] @ W1p^T -> cell -> h1_new (=hs slot t+1), c1
    gemm_k<1><<<dim3(64, 8), 256, 0, stream>>>(
        h0_new, HH, 256, h1_prev, HH,
        W1p, 512, bih1, bhh1, c1, h1_new,
        last ? hn_out + (size_t)BB * HH : (float*)nullptr,
        last ? cn_out + (size_t)BB * HH : (float*)nullptr);
  }

  out_gemm_mfma<<<1280, 256, 0, stream>>>(hs, Wob, b_out, out);
}